// Round 10
// baseline (715.487 us; speedup 1.0000x reference)
//
#include <hip/hip_runtime.h>

// ---------------------------------------------------------------------------
// A3TGCN2 TemporalGNN, MI355X (gfx950)
//
// Pipeline: memset(deg/cursor), k_deg, k_prep(pack), k_scan(+dinv), k_csr,
//           k_agg, k_gru
//
// R1: 12x unroll -> spill.  R2: launch_bounds VGPR cap -> spill.
// R3: pointer-passed local arrays never promoted -> named float4 X-macros.
// R4/R5: macro token-pasting traps.
// R6: global uniform weight reads: latency-serialized (496us).
// R7: lane-split weights -> lane-varying pointers -> spill. REVERTED.
// R8: LDS weights, unbounded scheduling -> ds_read clustering -> spill.
// R9: LDS weights + sched_barrier(0) per 32-float row: k_gru fixed
//     (<300us, out of top-5). New bottleneck: k_agg 303us, latency x MLP
//     bound (3 waves/SIMD x 12 gathers in flight = 0.5MB < BW*lat ~1MB).
// R10: k_agg processes 2 edges/iteration -> 24 float4 gathers in flight
//     (~170 VGPR, still 3 waves/SIMD = grid-supplied). unroll 1 guards.
// ---------------------------------------------------------------------------

#define NN 50000
#define NE 800000
#define FIN 8
#define PER 12
#define HID 32
#define BATCH 2
#define FP 96                 // FIN*PER
#define BN (BATCH * NN)
#define OUTF 24               // PER*NTF

// packed parameter block (floats): probs | 3x[M|Lbot|c] | Wout | bout
#define OFF_PROBS  0          // 12 (pad to 16)
#define OFF_WPK    16
#define GSTRIDE    1312       // [8x32 M][32x32 Lbot][32 c]
#define OFF_WOUT   3952       // 32 x 24 (row-major)
#define OFF_BOUT   4720       // 24
#define SM_TOT     4744       // 18976 B of LDS

// workspace layout (float units)
#define OFF_DINV   4744       // N floats
#define OFF_DEGI   54744      // N ints (contiguous with cursor for memset)
#define OFF_CURSOR 104744     // N ints
#define OFF_ROWPTR 154744     // N+1 ints
#define OFF_COL    204752     // E ints
#define OFF_WGT    1004752    // E floats
#define OFF_AX     1804752    // 96 * B*N floats
#define WS_FLOATS  11404752   // ~45.6 MB needed

__device__ __forceinline__ float fast_exp2(float x) {
#if __has_builtin(__builtin_amdgcn_exp2f)
    return __builtin_amdgcn_exp2f(x);
#else
    return exp2f(x);
#endif
}
__device__ __forceinline__ float fast_rcp(float x) {
#if __has_builtin(__builtin_amdgcn_rcpf)
    return __builtin_amdgcn_rcpf(x);
#else
    return 1.0f / x;
#endif
}
__device__ __forceinline__ float sigm(float x) {
    return fast_rcp(1.0f + fast_exp2(-1.4426950408889634f * x));
}
__device__ __forceinline__ float tanh_fast(float x) {
    return 2.0f * fast_rcp(1.0f + fast_exp2(-2.8853900817779268f * x)) - 1.0f;
}

__global__ void k_deg(const int* __restrict__ dst, int* __restrict__ degi) {
    int e = blockIdx.x * blockDim.x + threadIdx.x;
    if (e < NE) atomicAdd(&degi[dst[e]], 1);
}

// Packs: probs, per-gate [M(8x32) | Lbot(32x32) | c(32)], Wout, bout.
__global__ void k_prep(const float* __restrict__ att,
                       const float* __restrict__ Wz, const float* __restrict__ bz,
                       const float* __restrict__ Wr, const float* __restrict__ br,
                       const float* __restrict__ Wh, const float* __restrict__ bh,
                       const float* __restrict__ Lz, const float* __restrict__ lbz,
                       const float* __restrict__ Lr, const float* __restrict__ lbr,
                       const float* __restrict__ Lh, const float* __restrict__ lbh,
                       const float* __restrict__ Wout, const float* __restrict__ bout,
                       float* __restrict__ ws) {
    int tid = threadIdx.x;
    if (tid == 0) {
        float a[PER], m = -1e30f, s = 0.0f;
        for (int i = 0; i < PER; i++) { a[i] = att[i]; m = fmaxf(m, a[i]); }
        for (int i = 0; i < PER; i++) { a[i] = __expf(a[i] - m); s += a[i]; }
        for (int i = 0; i < PER; i++) ws[OFF_PROBS + i] = a[i] / s;
    }
    int k = tid >> 5, j = tid & 31;   // k in [0,8), j in [0,32)
    const float* Ws[3]  = { Wz, Wr, Wh };
    const float* Ls[3]  = { Lz, Lr, Lh };
    const float* bs[3]  = { bz, br, bh };
    const float* lbs[3] = { lbz, lbr, lbh };
    for (int g = 0; g < 3; g++) {
        float* wp = ws + OFF_WPK + g * GSTRIDE;
        float acc = 0.0f;
        for (int i = 0; i < HID; i++) acc += Ws[g][k * HID + i] * Ls[g][i * HID + j];
        wp[k * HID + j] = acc;
        for (int i = tid; i < 1024; i += 256) wp[256 + i] = Ls[g][1024 + i];
        if (tid < HID) {
            float c = lbs[g][tid];
            for (int i = 0; i < HID; i++) c += bs[g][i] * Ls[g][i * HID + tid];
            wp[1280 + tid] = c;
        }
    }
    for (int i = tid; i < 768; i += 256) ws[OFF_WOUT + i] = Wout[i];
    if (tid < OUTF) ws[OFF_BOUT + tid] = bout[tid];
}

// strip scan: 1024 threads x STRIP elements; also computes dinv. One block.
#define STRIP 49   // ceil(50000/1024)
__global__ __launch_bounds__(1024)
void k_scan(const int* __restrict__ degi, int* __restrict__ rowptr,
            float* __restrict__ dinv) {
    __shared__ int wsum[16];
    int tid = threadIdx.x;
    int lane = tid & 63, wid = tid >> 6;
    int s0 = tid * STRIP;
    int vals[STRIP];
    int sum = 0;
    #pragma unroll
    for (int i = 0; i < STRIP; i++) {
        int idx = s0 + i;
        int d = (idx < NN) ? degi[idx] : 0;
        vals[i] = d;
        sum += d;
        if (idx < NN) dinv[idx] = rsqrtf(1.0f + (float)d);
    }
    int run = sum;
    #pragma unroll
    for (int off = 1; off < 64; off <<= 1) {
        int t = __shfl_up(run, off);
        if (lane >= off) run += t;
    }
    if (lane == 63) wsum[wid] = run;
    __syncthreads();
    if (wid == 0 && lane < 16) {
        int v = wsum[lane];
        #pragma unroll
        for (int off = 1; off < 16; off <<= 1) {
            int t = __shfl_up(v, off);
            if (lane >= off) v += t;
        }
        wsum[lane] = v;
    }
    __syncthreads();
    int base = (wid ? wsum[wid - 1] : 0) + (run - sum);
    if (tid == 0) rowptr[0] = 0;
    #pragma unroll
    for (int i = 0; i < STRIP; i++) {
        int idx = s0 + i;
        if (idx < NN) { base += vals[i]; rowptr[idx + 1] = base; }
    }
}

__global__ void k_csr(const int* __restrict__ src, const int* __restrict__ dst,
                      const int* __restrict__ rowptr, int* __restrict__ cursor,
                      const float* __restrict__ dinv,
                      int* __restrict__ col, float* __restrict__ wgt) {
    int e = blockIdx.x * blockDim.x + threadIdx.x;
    if (e >= NE) return;
    int s = src[e], d = dst[e];
    int pos = atomicAdd(&cursor[d], 1);
    int i = rowptr[d] + pos;
    col[i] = s;
    wgt[i] = dinv[s] * dinv[d];
}

// 6 chunks of 4 floats per thread; gridDim.y = 4 covers the 96 (f,p) values.
// R10: 2 edges per iteration -> 24 independent float4 gathers in flight.
__global__ void k_agg(const float* __restrict__ x,
                      const int* __restrict__ rowptr, const int* __restrict__ col,
                      const float* __restrict__ wgt, const float* __restrict__ dinv,
                      float* __restrict__ AX) {
    int n = blockIdx.x * blockDim.x + threadIdx.x;
    if (n >= NN) return;
    int cb = blockIdx.y * 24;             // float offset base (6 float4 chunks)
    int r0 = rowptr[n], r1 = rowptr[n + 1];
    float4 a0[6], a1[6];
    #pragma unroll
    for (int cc = 0; cc < 6; cc++) {
        a0[cc] = make_float4(0.f, 0.f, 0.f, 0.f);
        a1[cc] = make_float4(0.f, 0.f, 0.f, 0.f);
    }
    int i = r0;
    #pragma unroll 1
    for (; i + 2 <= r1; i += 2) {
        int sA = col[i], sB = col[i + 1];
        float wA = wgt[i], wB = wgt[i + 1];
        const float* pA0 = x + (size_t)sA * FP + cb;
        const float* pA1 = pA0 + (size_t)NN * FP;
        const float* pB0 = x + (size_t)sB * FP + cb;
        const float* pB1 = pB0 + (size_t)NN * FP;
        float4 vA0[6], vA1[6], vB0[6], vB1[6];
        #pragma unroll
        for (int cc = 0; cc < 6; cc++) {
            vA0[cc] = *(const float4*)(pA0 + cc * 4);
            vA1[cc] = *(const float4*)(pA1 + cc * 4);
            vB0[cc] = *(const float4*)(pB0 + cc * 4);
            vB1[cc] = *(const float4*)(pB1 + cc * 4);
        }
        #pragma unroll
        for (int cc = 0; cc < 6; cc++) {
            a0[cc].x = fmaf(wA, vA0[cc].x, fmaf(wB, vB0[cc].x, a0[cc].x));
            a0[cc].y = fmaf(wA, vA0[cc].y, fmaf(wB, vB0[cc].y, a0[cc].y));
            a0[cc].z = fmaf(wA, vA0[cc].z, fmaf(wB, vB0[cc].z, a0[cc].z));
            a0[cc].w = fmaf(wA, vA0[cc].w, fmaf(wB, vB0[cc].w, a0[cc].w));
            a1[cc].x = fmaf(wA, vA1[cc].x, fmaf(wB, vB1[cc].x, a1[cc].x));
            a1[cc].y = fmaf(wA, vA1[cc].y, fmaf(wB, vB1[cc].y, a1[cc].y));
            a1[cc].z = fmaf(wA, vA1[cc].z, fmaf(wB, vB1[cc].z, a1[cc].z));
            a1[cc].w = fmaf(wA, vA1[cc].w, fmaf(wB, vB1[cc].w, a1[cc].w));
        }
    }
    #pragma unroll 1
    for (; i < r1; i++) {                 // tail edge (odd degree)
        int s = col[i];
        float w = wgt[i];
        const float* xb0 = x + (size_t)s * FP + cb;
        const float* xb1 = xb0 + (size_t)NN * FP;
        #pragma unroll
        for (int cc = 0; cc < 6; cc++) {
            float4 v0 = *(const float4*)(xb0 + cc * 4);
            float4 v1 = *(const float4*)(xb1 + cc * 4);
            a0[cc].x = fmaf(w, v0.x, a0[cc].x); a0[cc].y = fmaf(w, v0.y, a0[cc].y);
            a0[cc].z = fmaf(w, v0.z, a0[cc].z); a0[cc].w = fmaf(w, v0.w, a0[cc].w);
            a1[cc].x = fmaf(w, v1.x, a1[cc].x); a1[cc].y = fmaf(w, v1.y, a1[cc].y);
            a1[cc].z = fmaf(w, v1.z, a1[cc].z); a1[cc].w = fmaf(w, v1.w, a1[cc].w);
        }
    }
    {   // self loop: weight dinv[n]^2
        float di = dinv[n];
        float w = di * di;
        const float* xb0 = x + (size_t)n * FP + cb;
        const float* xb1 = xb0 + (size_t)NN * FP;
        #pragma unroll
        for (int cc = 0; cc < 6; cc++) {
            float4 v0 = *(const float4*)(xb0 + cc * 4);
            float4 v1 = *(const float4*)(xb1 + cc * 4);
            a0[cc].x = fmaf(w, v0.x, a0[cc].x); a0[cc].y = fmaf(w, v0.y, a0[cc].y);
            a0[cc].z = fmaf(w, v0.z, a0[cc].z); a0[cc].w = fmaf(w, v0.w, a0[cc].w);
            a1[cc].x = fmaf(w, v1.x, a1[cc].x); a1[cc].y = fmaf(w, v1.y, a1[cc].y);
            a1[cc].z = fmaf(w, v1.z, a1[cc].z); a1[cc].w = fmaf(w, v1.w, a1[cc].w);
        }
    }
    #pragma unroll
    for (int cc = 0; cc < 6; cc++) {
        int q = cb + cc * 4;
        AX[(size_t)(q + 0) * BN + n] = a0[cc].x;
        AX[(size_t)(q + 1) * BN + n] = a0[cc].y;
        AX[(size_t)(q + 2) * BN + n] = a0[cc].z;
        AX[(size_t)(q + 3) * BN + n] = a0[cc].w;
        AX[(size_t)(q + 0) * BN + NN + n] = a1[cc].x;
        AX[(size_t)(q + 1) * BN + NN + n] = a1[cc].y;
        AX[(size_t)(q + 2) * BN + NN + n] = a1[cc].z;
        AX[(size_t)(q + 3) * BN + NN + n] = a1[cc].w;
    }
}

// ----- array-free GRU machinery: X-macros over 8 float4s (32 lanes) -----

#define FOR32(OP) \
    OP(0,x,0)  OP(0,y,1)  OP(0,z,2)  OP(0,w,3) \
    OP(1,x,4)  OP(1,y,5)  OP(1,z,6)  OP(1,w,7) \
    OP(2,x,8)  OP(2,y,9)  OP(2,z,10) OP(2,w,11) \
    OP(3,x,12) OP(3,y,13) OP(3,z,14) OP(3,w,15) \
    OP(4,x,16) OP(4,y,17) OP(4,z,18) OP(4,w,19) \
    OP(5,x,20) OP(5,y,21) OP(5,z,22) OP(5,w,23) \
    OP(6,x,24) OP(6,y,25) OP(6,z,26) OP(6,w,27) \
    OP(7,x,28) OP(7,y,29) OP(7,z,30) OP(7,w,31)

// component-wise fma; param names must not be x/y/z/w (R5 lesson)
#define FMA4(dd, ss, vv) \
    dd.x = fmaf((ss), (vv).x, dd.x); dd.y = fmaf((ss), (vv).y, dd.y); \
    dd.z = fmaf((ss), (vv).z, dd.z); dd.w = fmaf((ss), (vv).w, dd.w);

// schedule pin: nothing (loads OR fmas) crosses this point. Caps live
// ds_read data to one row (~32 VGPRs) -- the R8 spill preventer.
#define SBAR() __builtin_amdgcn_sched_barrier(0)

// P##0..P##7 += a * W[ofs .. ofs+31]; W is an LDS base, ofs compile-time
// -> ds_read_b128 with offset: immediate, uniform address (broadcast).
#define ROW(P, a, W, ofs) do { \
    float4 u0 = *(const float4*)((W) + (ofs)); \
    float4 u1 = *(const float4*)((W) + (ofs) + 4); \
    float4 u2 = *(const float4*)((W) + (ofs) + 8); \
    float4 u3 = *(const float4*)((W) + (ofs) + 12); \
    float4 u4 = *(const float4*)((W) + (ofs) + 16); \
    float4 u5 = *(const float4*)((W) + (ofs) + 20); \
    float4 u6 = *(const float4*)((W) + (ofs) + 24); \
    float4 u7 = *(const float4*)((W) + (ofs) + 28); \
    float av = (a); \
    FMA4(P##0, av, u0) FMA4(P##1, av, u1) FMA4(P##2, av, u2) FMA4(P##3, av, u3) \
    FMA4(P##4, av, u4) FMA4(P##5, av, u5) FMA4(P##6, av, u6) FMA4(P##7, av, u7) \
    SBAR(); \
} while (0)

#define LDB(P, W) \
    P##0 = *(const float4*)((W) + 1280); P##1 = *(const float4*)((W) + 1284); \
    P##2 = *(const float4*)((W) + 1288); P##3 = *(const float4*)((W) + 1292); \
    P##4 = *(const float4*)((W) + 1296); P##5 = *(const float4*)((W) + 1300); \
    P##6 = *(const float4*)((W) + 1304); P##7 = *(const float4*)((W) + 1308); \
    SBAR();

#define GATE_IN(P, W) \
    ROW(P, in0.x, W, 0);   ROW(P, in0.y, W, 32);  ROW(P, in0.z, W, 64);  ROW(P, in0.w, W, 96); \
    ROW(P, in1.x, W, 128); ROW(P, in1.y, W, 160); ROW(P, in1.z, W, 192); ROW(P, in1.w, W, 224);

#define GH_O_H(i,c,n) ROW(o, h##i.c, Wg, 256 + 32*(n));
#define GH_T_O(i,c,n) ROW(t, o##i.c, Wg, 256 + 32*(n));
#define ZERO_OP(i,c,n) h##i.c = 0.0f; ac##i.c = 0.0f;
#define HR_OP(i,c,n)   o##i.c = sigm(o##i.c) * h##i.c;
#define TANH_OP(i,c,n) t##i.c = tanh_fast(t##i.c);
#define UPD_OP(i,c,n)  { float Zv = sigm(o##i.c); \
                         h##i.c = fmaf(Zv, h##i.c - t##i.c, t##i.c); \
                         ac##i.c = fmaf(pp, h##i.c, ac##i.c); }

#define OROW(a, ofs) do { \
    float4 u0 = *(const float4*)(WO + (ofs)); \
    float4 u1 = *(const float4*)(WO + (ofs) + 4); \
    float4 u2 = *(const float4*)(WO + (ofs) + 8); \
    float4 u3 = *(const float4*)(WO + (ofs) + 12); \
    float4 u4 = *(const float4*)(WO + (ofs) + 16); \
    float4 u5 = *(const float4*)(WO + (ofs) + 20); \
    float av = (a); \
    FMA4(q0, av, u0) FMA4(q1, av, u1) FMA4(q2, av, u2) \
    FMA4(q3, av, u3) FMA4(q4, av, u4) FMA4(q5, av, u5) \
    SBAR(); \
} while (0)

#define OUT_OP(i,c,n) OROW(fmaxf(ac##i.c, 0.0f), (n) * OUTF);

__global__ __launch_bounds__(64)
void k_gru(const float* __restrict__ AX, const float* __restrict__ wp,
           float* __restrict__ out) {
    __shared__ __align__(16) float sm[SM_TOT];
    int tid = threadIdx.x;
    // stage all packed params into LDS once (loop-invariant across periods)
    for (int i = tid; i < SM_TOT; i += 64) sm[i] = wp[i];
    __syncthreads();

    int g = blockIdx.x * 64 + tid;   // g = b*N + n
    if (g >= BN) return;

    const float* WZ = sm + OFF_WPK;
    const float* WR = sm + OFF_WPK + GSTRIDE;
    const float* WH = sm + OFF_WPK + 2 * GSTRIDE;

    float4 h0, h1, h2, h3, h4, h5, h6, h7;
    float4 ac0, ac1, ac2, ac3, ac4, ac5, ac6, ac7;
    float4 o0, o1, o2, o3, o4, o5, o6, o7;
    float4 t0, t1, t2, t3, t4, t5, t6, t7;
    float4 in0, in1;
    FOR32(ZERO_OP)

    #pragma unroll 1
    for (int p = 0; p < PER; p++) {
        const float* axp = AX + (size_t)p * BN + g;
        in0.x = axp[0];
        in0.y = axp[(size_t)1 * PER * BN];
        in0.z = axp[(size_t)2 * PER * BN];
        in0.w = axp[(size_t)3 * PER * BN];
        in1.x = axp[(size_t)4 * PER * BN];
        in1.y = axp[(size_t)5 * PER * BN];
        in1.z = axp[(size_t)6 * PER * BN];
        in1.w = axp[(size_t)7 * PER * BN];
        float pp = sm[OFF_PROBS + p];

        // R gate -> o = sigm(R)*H
        { const float* Wg = WR; LDB(o, Wg); GATE_IN(o, Wg); FOR32(GH_O_H) }
        FOR32(HR_OP)
        // T gate (uses o = H*R) -> t = tanh(T)
        { const float* Wg = WH; LDB(t, Wg); GATE_IN(t, Wg); FOR32(GH_T_O) }
        FOR32(TANH_OP)
        // Z gate -> update H, acc
        { const float* Wg = WZ; LDB(o, Wg); GATE_IN(o, Wg); FOR32(GH_O_H) }
        FOR32(UPD_OP)
    }

    // epilogue: relu(acc) @ Wout + bout
    const float* WO = sm + OFF_WOUT;
    const float* WB = sm + OFF_BOUT;
    float4 q0 = *(const float4*)(WB + 0);
    float4 q1 = *(const float4*)(WB + 4);
    float4 q2 = *(const float4*)(WB + 8);
    float4 q3 = *(const float4*)(WB + 12);
    float4 q4 = *(const float4*)(WB + 16);
    float4 q5 = *(const float4*)(WB + 20);
    FOR32(OUT_OP)

    float* op = out + (size_t)g * OUTF;
    *(float4*)(op + 0)  = q0; *(float4*)(op + 4)  = q1;
    *(float4*)(op + 8)  = q2; *(float4*)(op + 12) = q3;
    *(float4*)(op + 16) = q4; *(float4*)(op + 20) = q5;
}

extern "C" void kernel_launch(void* const* d_in, const int* in_sizes, int n_in,
                              void* d_out, int out_size, void* d_ws, size_t ws_size,
                              hipStream_t stream) {
    if (ws_size < (size_t)WS_FLOATS * sizeof(float)) return;  // need ~45.6 MB scratch

    const float* x    = (const float*)d_in[0];
    const int*   ei   = (const int*)d_in[1];
    const float* att  = (const float*)d_in[2];
    const float* Wz   = (const float*)d_in[3];
    const float* bz   = (const float*)d_in[4];
    const float* Wr   = (const float*)d_in[5];
    const float* br   = (const float*)d_in[6];
    const float* Wh   = (const float*)d_in[7];
    const float* bh   = (const float*)d_in[8];
    const float* Lz   = (const float*)d_in[9];
    const float* lbz  = (const float*)d_in[10];
    const float* Lr   = (const float*)d_in[11];
    const float* lbr  = (const float*)d_in[12];
    const float* Lh   = (const float*)d_in[13];
    const float* lbh  = (const float*)d_in[14];
    const float* Wout = (const float*)d_in[15];
    const float* bout = (const float*)d_in[16];
    float* out = (float*)d_out;
    float* ws  = (float*)d_ws;

    const int* src = ei;
    const int* dst = ei + NE;

    float* dinv   = ws + OFF_DINV;
    int*   degi   = (int*)(ws + OFF_DEGI);
    int*   cursor = (int*)(ws + OFF_CURSOR);
    int*   rowptr = (int*)(ws + OFF_ROWPTR);
    int*   col    = (int*)(ws + OFF_COL);
    float* wgt    = ws + OFF_WGT;
    float* AX     = ws + OFF_AX;

    hipMemsetAsync(degi, 0, 2 * (size_t)NN * sizeof(int), stream);
    k_deg<<<(NE + 255) / 256, 256, 0, stream>>>(dst, degi);
    k_prep<<<1, 256, 0, stream>>>(att, Wz, bz, Wr, br, Wh, bh,
                                  Lz, lbz, Lr, lbr, Lh, lbh, Wout, bout, ws);
    k_scan<<<1, 1024, 0, stream>>>(degi, rowptr, dinv);
    k_csr<<<(NE + 255) / 256, 256, 0, stream>>>(src, dst, rowptr, cursor, dinv, col, wgt);
    dim3 gAgg((NN + 255) / 256, 4);
    k_agg<<<gAgg, 256, 0, stream>>>(x, rowptr, col, wgt, dinv, AX);
    k_gru<<<(BN + 63) / 64, 64, 0, stream>>>(AX, ws, out);
}

// Round 11
// 546.950 us; speedup vs baseline: 1.3081x; 1.3081x over previous
//
#include <hip/hip_runtime.h>

// ---------------------------------------------------------------------------
// A3TGCN2 TemporalGNN, MI355X (gfx950)
//
// Pipeline: memset(deg/cursor), k_deg, k_prep(pack), k_scan(+dinv), k_csr,
//           k_agg, k_gru
//
// R1: 12x unroll -> spill.  R2: launch_bounds VGPR cap -> spill.
// R3: pointer-passed local arrays never promoted -> named float4 X-macros.
// R4/R5: macro token-pasting traps.
// R6: global uniform weight reads: latency-serialized (496us).
// R7: lane-split weights -> lane-varying pointers -> spill. REVERTED.
// R8: LDS weights, unbounded scheduling -> ds_read clustering -> spill.
// R9: LDS weights + sched_barrier(0) per row: k_gru fixed (<300us).
// R10: 2-edge pairing in k_agg: NEUTRAL (compiler chained load->fma,
//      VGPR 56, MLP unchanged; FETCH rose 795->944MB).
// R11: k_agg root cause is line overfetch: y=4 feature-split reads 96B
//      chunks (1.5 lines each, 12 line-fetches/edge vs 6 ideal). Fix:
//      y=2 BATCH-PLANE split, each thread gathers the FULL 384B row
//      (24 float4, 3 lines exact) + sched_barrier-forced 24-deep load
//      cluster. col/wgt re-read 4x -> 2x.
// ---------------------------------------------------------------------------

#define NN 50000
#define NE 800000
#define FIN 8
#define PER 12
#define HID 32
#define BATCH 2
#define FP 96                 // FIN*PER
#define BN (BATCH * NN)
#define OUTF 24               // PER*NTF

// packed parameter block (floats): probs | 3x[M|Lbot|c] | Wout | bout
#define OFF_PROBS  0          // 12 (pad to 16)
#define OFF_WPK    16
#define GSTRIDE    1312       // [8x32 M][32x32 Lbot][32 c]
#define OFF_WOUT   3952       // 32 x 24 (row-major)
#define OFF_BOUT   4720       // 24
#define SM_TOT     4744       // 18976 B of LDS

// workspace layout (float units)
#define OFF_DINV   4744       // N floats
#define OFF_DEGI   54744      // N ints (contiguous with cursor for memset)
#define OFF_CURSOR 104744     // N ints
#define OFF_ROWPTR 154744     // N+1 ints
#define OFF_COL    204752     // E ints
#define OFF_WGT    1004752    // E floats
#define OFF_AX     1804752    // 96 * B*N floats
#define WS_FLOATS  11404752   // ~45.6 MB needed

__device__ __forceinline__ float fast_exp2(float x) {
#if __has_builtin(__builtin_amdgcn_exp2f)
    return __builtin_amdgcn_exp2f(x);
#else
    return exp2f(x);
#endif
}
__device__ __forceinline__ float fast_rcp(float x) {
#if __has_builtin(__builtin_amdgcn_rcpf)
    return __builtin_amdgcn_rcpf(x);
#else
    return 1.0f / x;
#endif
}
__device__ __forceinline__ float sigm(float x) {
    return fast_rcp(1.0f + fast_exp2(-1.4426950408889634f * x));
}
__device__ __forceinline__ float tanh_fast(float x) {
    return 2.0f * fast_rcp(1.0f + fast_exp2(-2.8853900817779268f * x)) - 1.0f;
}

__global__ void k_deg(const int* __restrict__ dst, int* __restrict__ degi) {
    int e = blockIdx.x * blockDim.x + threadIdx.x;
    if (e < NE) atomicAdd(&degi[dst[e]], 1);
}

// Packs: probs, per-gate [M(8x32) | Lbot(32x32) | c(32)], Wout, bout.
__global__ void k_prep(const float* __restrict__ att,
                       const float* __restrict__ Wz, const float* __restrict__ bz,
                       const float* __restrict__ Wr, const float* __restrict__ br,
                       const float* __restrict__ Wh, const float* __restrict__ bh,
                       const float* __restrict__ Lz, const float* __restrict__ lbz,
                       const float* __restrict__ Lr, const float* __restrict__ lbr,
                       const float* __restrict__ Lh, const float* __restrict__ lbh,
                       const float* __restrict__ Wout, const float* __restrict__ bout,
                       float* __restrict__ ws) {
    int tid = threadIdx.x;
    if (tid == 0) {
        float a[PER], m = -1e30f, s = 0.0f;
        for (int i = 0; i < PER; i++) { a[i] = att[i]; m = fmaxf(m, a[i]); }
        for (int i = 0; i < PER; i++) { a[i] = __expf(a[i] - m); s += a[i]; }
        for (int i = 0; i < PER; i++) ws[OFF_PROBS + i] = a[i] / s;
    }
    int k = tid >> 5, j = tid & 31;   // k in [0,8), j in [0,32)
    const float* Ws[3]  = { Wz, Wr, Wh };
    const float* Ls[3]  = { Lz, Lr, Lh };
    const float* bs[3]  = { bz, br, bh };
    const float* lbs[3] = { lbz, lbr, lbh };
    for (int g = 0; g < 3; g++) {
        float* wp = ws + OFF_WPK + g * GSTRIDE;
        float acc = 0.0f;
        for (int i = 0; i < HID; i++) acc += Ws[g][k * HID + i] * Ls[g][i * HID + j];
        wp[k * HID + j] = acc;
        for (int i = tid; i < 1024; i += 256) wp[256 + i] = Ls[g][1024 + i];
        if (tid < HID) {
            float c = lbs[g][tid];
            for (int i = 0; i < HID; i++) c += bs[g][i] * Ls[g][i * HID + tid];
            wp[1280 + tid] = c;
        }
    }
    for (int i = tid; i < 768; i += 256) ws[OFF_WOUT + i] = Wout[i];
    if (tid < OUTF) ws[OFF_BOUT + tid] = bout[tid];
}

// strip scan: 1024 threads x STRIP elements; also computes dinv. One block.
#define STRIP 49   // ceil(50000/1024)
__global__ __launch_bounds__(1024)
void k_scan(const int* __restrict__ degi, int* __restrict__ rowptr,
            float* __restrict__ dinv) {
    __shared__ int wsum[16];
    int tid = threadIdx.x;
    int lane = tid & 63, wid = tid >> 6;
    int s0 = tid * STRIP;
    int vals[STRIP];
    int sum = 0;
    #pragma unroll
    for (int i = 0; i < STRIP; i++) {
        int idx = s0 + i;
        int d = (idx < NN) ? degi[idx] : 0;
        vals[i] = d;
        sum += d;
        if (idx < NN) dinv[idx] = rsqrtf(1.0f + (float)d);
    }
    int run = sum;
    #pragma unroll
    for (int off = 1; off < 64; off <<= 1) {
        int t = __shfl_up(run, off);
        if (lane >= off) run += t;
    }
    if (lane == 63) wsum[wid] = run;
    __syncthreads();
    if (wid == 0 && lane < 16) {
        int v = wsum[lane];
        #pragma unroll
        for (int off = 1; off < 16; off <<= 1) {
            int t = __shfl_up(v, off);
            if (lane >= off) v += t;
        }
        wsum[lane] = v;
    }
    __syncthreads();
    int base = (wid ? wsum[wid - 1] : 0) + (run - sum);
    if (tid == 0) rowptr[0] = 0;
    #pragma unroll
    for (int i = 0; i < STRIP; i++) {
        int idx = s0 + i;
        if (idx < NN) { base += vals[i]; rowptr[idx + 1] = base; }
    }
}

__global__ void k_csr(const int* __restrict__ src, const int* __restrict__ dst,
                      const int* __restrict__ rowptr, int* __restrict__ cursor,
                      const float* __restrict__ dinv,
                      int* __restrict__ col, float* __restrict__ wgt) {
    int e = blockIdx.x * blockDim.x + threadIdx.x;
    if (e >= NE) return;
    int s = src[e], d = dst[e];
    int pos = atomicAdd(&cursor[d], 1);
    int i = rowptr[d] + pos;
    col[i] = s;
    wgt[i] = dinv[s] * dinv[d];
}

// R11: gridDim.y = 2 batch planes; each thread gathers FULL 384B rows
// (24 x float4, exactly 3 cache lines, zero overfetch). sched_barrier
// after the load block forces a 24-deep load cluster (real MLP).
__global__ __launch_bounds__(256)
void k_agg(const float* __restrict__ x,
           const int* __restrict__ rowptr, const int* __restrict__ col,
           const float* __restrict__ wgt, const float* __restrict__ dinv,
           float* __restrict__ AX) {
    int n = blockIdx.x * blockDim.x + threadIdx.x;
    if (n >= NN) return;
    const float* xb = x + (size_t)blockIdx.y * (NN * FP);   // plane base
    float* axb = AX + (size_t)blockIdx.y * NN + n;          // AX[q*BN + b*NN + n]
    int r0 = rowptr[n], r1 = rowptr[n + 1];

    float4 acc[24];
    #pragma unroll
    for (int c = 0; c < 24; c++) acc[c] = make_float4(0.f, 0.f, 0.f, 0.f);

    #pragma unroll 1
    for (int i = r0; i < r1; i++) {
        int s = col[i];
        float w = wgt[i];
        const float* row = xb + (size_t)s * FP;
        float4 v[24];
        #pragma unroll
        for (int c = 0; c < 24; c++) v[c] = *(const float4*)(row + c * 4);
        __builtin_amdgcn_sched_barrier(0);   // keep all 24 loads clustered
        #pragma unroll
        for (int c = 0; c < 24; c++) {
            acc[c].x = fmaf(w, v[c].x, acc[c].x);
            acc[c].y = fmaf(w, v[c].y, acc[c].y);
            acc[c].z = fmaf(w, v[c].z, acc[c].z);
            acc[c].w = fmaf(w, v[c].w, acc[c].w);
        }
    }
    {   // self loop: weight dinv[n]^2
        float di = dinv[n];
        float w = di * di;
        const float* row = xb + (size_t)n * FP;
        float4 v[24];
        #pragma unroll
        for (int c = 0; c < 24; c++) v[c] = *(const float4*)(row + c * 4);
        __builtin_amdgcn_sched_barrier(0);
        #pragma unroll
        for (int c = 0; c < 24; c++) {
            acc[c].x = fmaf(w, v[c].x, acc[c].x);
            acc[c].y = fmaf(w, v[c].y, acc[c].y);
            acc[c].z = fmaf(w, v[c].z, acc[c].z);
            acc[c].w = fmaf(w, v[c].w, acc[c].w);
        }
    }
    #pragma unroll
    for (int c = 0; c < 24; c++) {
        axb[(size_t)(4 * c + 0) * BN] = acc[c].x;
        axb[(size_t)(4 * c + 1) * BN] = acc[c].y;
        axb[(size_t)(4 * c + 2) * BN] = acc[c].z;
        axb[(size_t)(4 * c + 3) * BN] = acc[c].w;
    }
}

// ----- array-free GRU machinery: X-macros over 8 float4s (32 lanes) -----

#define FOR32(OP) \
    OP(0,x,0)  OP(0,y,1)  OP(0,z,2)  OP(0,w,3) \
    OP(1,x,4)  OP(1,y,5)  OP(1,z,6)  OP(1,w,7) \
    OP(2,x,8)  OP(2,y,9)  OP(2,z,10) OP(2,w,11) \
    OP(3,x,12) OP(3,y,13) OP(3,z,14) OP(3,w,15) \
    OP(4,x,16) OP(4,y,17) OP(4,z,18) OP(4,w,19) \
    OP(5,x,20) OP(5,y,21) OP(5,z,22) OP(5,w,23) \
    OP(6,x,24) OP(6,y,25) OP(6,z,26) OP(6,w,27) \
    OP(7,x,28) OP(7,y,29) OP(7,z,30) OP(7,w,31)

// component-wise fma; param names must not be x/y/z/w (R5 lesson)
#define FMA4(dd, ss, vv) \
    dd.x = fmaf((ss), (vv).x, dd.x); dd.y = fmaf((ss), (vv).y, dd.y); \
    dd.z = fmaf((ss), (vv).z, dd.z); dd.w = fmaf((ss), (vv).w, dd.w);

// schedule pin: nothing (loads OR fmas) crosses this point. Caps live
// ds_read data to one row (~32 VGPRs) -- the R8 spill preventer.
#define SBAR() __builtin_amdgcn_sched_barrier(0)

// P##0..P##7 += a * W[ofs .. ofs+31]; W is an LDS base, ofs compile-time
// -> ds_read_b128 with offset: immediate, uniform address (broadcast).
#define ROW(P, a, W, ofs) do { \
    float4 u0 = *(const float4*)((W) + (ofs)); \
    float4 u1 = *(const float4*)((W) + (ofs) + 4); \
    float4 u2 = *(const float4*)((W) + (ofs) + 8); \
    float4 u3 = *(const float4*)((W) + (ofs) + 12); \
    float4 u4 = *(const float4*)((W) + (ofs) + 16); \
    float4 u5 = *(const float4*)((W) + (ofs) + 20); \
    float4 u6 = *(const float4*)((W) + (ofs) + 24); \
    float4 u7 = *(const float4*)((W) + (ofs) + 28); \
    float av = (a); \
    FMA4(P##0, av, u0) FMA4(P##1, av, u1) FMA4(P##2, av, u2) FMA4(P##3, av, u3) \
    FMA4(P##4, av, u4) FMA4(P##5, av, u5) FMA4(P##6, av, u6) FMA4(P##7, av, u7) \
    SBAR(); \
} while (0)

#define LDB(P, W) \
    P##0 = *(const float4*)((W) + 1280); P##1 = *(const float4*)((W) + 1284); \
    P##2 = *(const float4*)((W) + 1288); P##3 = *(const float4*)((W) + 1292); \
    P##4 = *(const float4*)((W) + 1296); P##5 = *(const float4*)((W) + 1300); \
    P##6 = *(const float4*)((W) + 1304); P##7 = *(const float4*)((W) + 1308); \
    SBAR();

#define GATE_IN(P, W) \
    ROW(P, in0.x, W, 0);   ROW(P, in0.y, W, 32);  ROW(P, in0.z, W, 64);  ROW(P, in0.w, W, 96); \
    ROW(P, in1.x, W, 128); ROW(P, in1.y, W, 160); ROW(P, in1.z, W, 192); ROW(P, in1.w, W, 224);

#define GH_O_H(i,c,n) ROW(o, h##i.c, Wg, 256 + 32*(n));
#define GH_T_O(i,c,n) ROW(t, o##i.c, Wg, 256 + 32*(n));
#define ZERO_OP(i,c,n) h##i.c = 0.0f; ac##i.c = 0.0f;
#define HR_OP(i,c,n)   o##i.c = sigm(o##i.c) * h##i.c;
#define TANH_OP(i,c,n) t##i.c = tanh_fast(t##i.c);
#define UPD_OP(i,c,n)  { float Zv = sigm(o##i.c); \
                         h##i.c = fmaf(Zv, h##i.c - t##i.c, t##i.c); \
                         ac##i.c = fmaf(pp, h##i.c, ac##i.c); }

#define OROW(a, ofs) do { \
    float4 u0 = *(const float4*)(WO + (ofs)); \
    float4 u1 = *(const float4*)(WO + (ofs) + 4); \
    float4 u2 = *(const float4*)(WO + (ofs) + 8); \
    float4 u3 = *(const float4*)(WO + (ofs) + 12); \
    float4 u4 = *(const float4*)(WO + (ofs) + 16); \
    float4 u5 = *(const float4*)(WO + (ofs) + 20); \
    float av = (a); \
    FMA4(q0, av, u0) FMA4(q1, av, u1) FMA4(q2, av, u2) \
    FMA4(q3, av, u3) FMA4(q4, av, u4) FMA4(q5, av, u5) \
    SBAR(); \
} while (0)

#define OUT_OP(i,c,n) OROW(fmaxf(ac##i.c, 0.0f), (n) * OUTF);

__global__ __launch_bounds__(64)
void k_gru(const float* __restrict__ AX, const float* __restrict__ wp,
           float* __restrict__ out) {
    __shared__ __align__(16) float sm[SM_TOT];
    int tid = threadIdx.x;
    // stage all packed params into LDS once (loop-invariant across periods)
    for (int i = tid; i < SM_TOT; i += 64) sm[i] = wp[i];
    __syncthreads();

    int g = blockIdx.x * 64 + tid;   // g = b*N + n
    if (g >= BN) return;

    const float* WZ = sm + OFF_WPK;
    const float* WR = sm + OFF_WPK + GSTRIDE;
    const float* WH = sm + OFF_WPK + 2 * GSTRIDE;

    float4 h0, h1, h2, h3, h4, h5, h6, h7;
    float4 ac0, ac1, ac2, ac3, ac4, ac5, ac6, ac7;
    float4 o0, o1, o2, o3, o4, o5, o6, o7;
    float4 t0, t1, t2, t3, t4, t5, t6, t7;
    float4 in0, in1;
    FOR32(ZERO_OP)

    #pragma unroll 1
    for (int p = 0; p < PER; p++) {
        const float* axp = AX + (size_t)p * BN + g;
        in0.x = axp[0];
        in0.y = axp[(size_t)1 * PER * BN];
        in0.z = axp[(size_t)2 * PER * BN];
        in0.w = axp[(size_t)3 * PER * BN];
        in1.x = axp[(size_t)4 * PER * BN];
        in1.y = axp[(size_t)5 * PER * BN];
        in1.z = axp[(size_t)6 * PER * BN];
        in1.w = axp[(size_t)7 * PER * BN];
        float pp = sm[OFF_PROBS + p];

        // R gate -> o = sigm(R)*H
        { const float* Wg = WR; LDB(o, Wg); GATE_IN(o, Wg); FOR32(GH_O_H) }
        FOR32(HR_OP)
        // T gate (uses o = H*R) -> t = tanh(T)
        { const float* Wg = WH; LDB(t, Wg); GATE_IN(t, Wg); FOR32(GH_T_O) }
        FOR32(TANH_OP)
        // Z gate -> update H, acc
        { const float* Wg = WZ; LDB(o, Wg); GATE_IN(o, Wg); FOR32(GH_O_H) }
        FOR32(UPD_OP)
    }

    // epilogue: relu(acc) @ Wout + bout
    const float* WO = sm + OFF_WOUT;
    const float* WB = sm + OFF_BOUT;
    float4 q0 = *(const float4*)(WB + 0);
    float4 q1 = *(const float4*)(WB + 4);
    float4 q2 = *(const float4*)(WB + 8);
    float4 q3 = *(const float4*)(WB + 12);
    float4 q4 = *(const float4*)(WB + 16);
    float4 q5 = *(const float4*)(WB + 20);
    FOR32(OUT_OP)

    float* op = out + (size_t)g * OUTF;
    *(float4*)(op + 0)  = q0; *(float4*)(op + 4)  = q1;
    *(float4*)(op + 8)  = q2; *(float4*)(op + 12) = q3;
    *(float4*)(op + 16) = q4; *(float4*)(op + 20) = q5;
}

extern "C" void kernel_launch(void* const* d_in, const int* in_sizes, int n_in,
                              void* d_out, int out_size, void* d_ws, size_t ws_size,
                              hipStream_t stream) {
    if (ws_size < (size_t)WS_FLOATS * sizeof(float)) return;  // need ~45.6 MB scratch

    const float* x    = (const float*)d_in[0];
    const int*   ei   = (const int*)d_in[1];
    const float* att  = (const float*)d_in[2];
    const float* Wz   = (const float*)d_in[3];
    const float* bz   = (const float*)d_in[4];
    const float* Wr   = (const float*)d_in[5];
    const float* br   = (const float*)d_in[6];
    const float* Wh   = (const float*)d_in[7];
    const float* bh   = (const float*)d_in[8];
    const float* Lz   = (const float*)d_in[9];
    const float* lbz  = (const float*)d_in[10];
    const float* Lr   = (const float*)d_in[11];
    const float* lbr  = (const float*)d_in[12];
    const float* Lh   = (const float*)d_in[13];
    const float* lbh  = (const float*)d_in[14];
    const float* Wout = (const float*)d_in[15];
    const float* bout = (const float*)d_in[16];
    float* out = (float*)d_out;
    float* ws  = (float*)d_ws;

    const int* src = ei;
    const int* dst = ei + NE;

    float* dinv   = ws + OFF_DINV;
    int*   degi   = (int*)(ws + OFF_DEGI);
    int*   cursor = (int*)(ws + OFF_CURSOR);
    int*   rowptr = (int*)(ws + OFF_ROWPTR);
    int*   col    = (int*)(ws + OFF_COL);
    float* wgt    = ws + OFF_WGT;
    float* AX     = ws + OFF_AX;

    hipMemsetAsync(degi, 0, 2 * (size_t)NN * sizeof(int), stream);
    k_deg<<<(NE + 255) / 256, 256, 0, stream>>>(dst, degi);
    k_prep<<<1, 256, 0, stream>>>(att, Wz, bz, Wr, br, Wh, bh,
                                  Lz, lbz, Lr, lbr, Lh, lbh, Wout, bout, ws);
    k_scan<<<1, 1024, 0, stream>>>(degi, rowptr, dinv);
    k_csr<<<(NE + 255) / 256, 256, 0, stream>>>(src, dst, rowptr, cursor, dinv, col, wgt);
    dim3 gAgg((NN + 255) / 256, 2);
    k_agg<<<gAgg, 256, 0, stream>>>(x, rowptr, col, wgt, dinv, AX);
    k_gru<<<(BN + 63) / 64, 64, 0, stream>>>(AX, ws, out);
}

// Round 13
// 545.973 us; speedup vs baseline: 1.3105x; 1.0018x over previous
//
#include <hip/hip_runtime.h>

// ---------------------------------------------------------------------------
// A3TGCN2 TemporalGNN, MI355X (gfx950)
//
// Pipeline: memset(deg/cursor), k_deg, k_prep(pack), k_scan(+dinv), k_csr,
//           k_agg, k_gru
//
// R1: 12x unroll -> spill.  R2: launch_bounds VGPR cap -> spill.
// R3: pointer-passed local arrays never promoted -> named float4 X-macros.
// R4/R5: macro token-pasting traps (pp-numbers, member-name params).
// R6: global uniform weight reads: latency-serialized (496us).
// R7: lane-split weights -> lane-varying pointers -> spill. REVERTED.
// R8: LDS weights, unbounded scheduling -> ds_read clustering -> spill.
// R9: LDS weights + sched_barrier(0) per row: k_gru 228us, no spill.
// R10: 2-edge pairing in k_agg: NEUTRAL. R11: full-row gather: k_agg fixed.
// R12: 2-deep pipeline: [load row k+1 || FMA row k] SBAR; live weight data
//      bounded at 2 rows by construction.
// R12 compile lesson: ## suppresses argument pre-expansion -> `GP##0` gave
//      GP0. Fix: deferred concat XCAT(a,b)->XCAT_(a,b)->a##b so GP expands
//      to o/t BEFORE pasting.
// ---------------------------------------------------------------------------

#define NN 50000
#define NE 800000
#define FIN 8
#define PER 12
#define HID 32
#define BATCH 2
#define FP 96                 // FIN*PER
#define BN (BATCH * NN)
#define OUTF 24               // PER*NTF

// packed parameter block (floats): probs | 3x[M|Lbot|c] | Wout | bout
#define OFF_PROBS  0          // 12 (pad to 16)
#define OFF_WPK    16
#define GSTRIDE    1312       // [8x32 M][32x32 Lbot][32 c]
#define OFF_WOUT   3952       // 32 x 24 (row-major)
#define OFF_BOUT   4720       // 24
#define SM_TOT     4744       // 18976 B of LDS

// workspace layout (float units)
#define OFF_DINV   4744       // N floats
#define OFF_DEGI   54744      // N ints (contiguous with cursor for memset)
#define OFF_CURSOR 104744     // N ints
#define OFF_ROWPTR 154744     // N+1 ints
#define OFF_COL    204752     // E ints
#define OFF_WGT    1004752    // E floats
#define OFF_AX     1804752    // 96 * B*N floats
#define WS_FLOATS  11404752   // ~45.6 MB needed

__device__ __forceinline__ float fast_exp2(float x) {
#if __has_builtin(__builtin_amdgcn_exp2f)
    return __builtin_amdgcn_exp2f(x);
#else
    return exp2f(x);
#endif
}
__device__ __forceinline__ float fast_rcp(float x) {
#if __has_builtin(__builtin_amdgcn_rcpf)
    return __builtin_amdgcn_rcpf(x);
#else
    return 1.0f / x;
#endif
}
__device__ __forceinline__ float sigm(float x) {
    return fast_rcp(1.0f + fast_exp2(-1.4426950408889634f * x));
}
__device__ __forceinline__ float tanh_fast(float x) {
    return 2.0f * fast_rcp(1.0f + fast_exp2(-2.8853900817779268f * x)) - 1.0f;
}

__global__ void k_deg(const int* __restrict__ dst, int* __restrict__ degi) {
    int e = blockIdx.x * blockDim.x + threadIdx.x;
    if (e < NE) atomicAdd(&degi[dst[e]], 1);
}

// Packs: probs, per-gate [M(8x32) | Lbot(32x32) | c(32)], Wout, bout.
__global__ void k_prep(const float* __restrict__ att,
                       const float* __restrict__ Wz, const float* __restrict__ bz,
                       const float* __restrict__ Wr, const float* __restrict__ br,
                       const float* __restrict__ Wh, const float* __restrict__ bh,
                       const float* __restrict__ Lz, const float* __restrict__ lbz,
                       const float* __restrict__ Lr, const float* __restrict__ lbr,
                       const float* __restrict__ Lh, const float* __restrict__ lbh,
                       const float* __restrict__ Wout, const float* __restrict__ bout,
                       float* __restrict__ ws) {
    int tid = threadIdx.x;
    if (tid == 0) {
        float a[PER], m = -1e30f, s = 0.0f;
        for (int i = 0; i < PER; i++) { a[i] = att[i]; m = fmaxf(m, a[i]); }
        for (int i = 0; i < PER; i++) { a[i] = __expf(a[i] - m); s += a[i]; }
        for (int i = 0; i < PER; i++) ws[OFF_PROBS + i] = a[i] / s;
    }
    int k = tid >> 5, j = tid & 31;   // k in [0,8), j in [0,32)
    const float* Ws[3]  = { Wz, Wr, Wh };
    const float* Ls[3]  = { Lz, Lr, Lh };
    const float* bs[3]  = { bz, br, bh };
    const float* lbs[3] = { lbz, lbr, lbh };
    for (int g = 0; g < 3; g++) {
        float* wp = ws + OFF_WPK + g * GSTRIDE;
        float acc = 0.0f;
        for (int i = 0; i < HID; i++) acc += Ws[g][k * HID + i] * Ls[g][i * HID + j];
        wp[k * HID + j] = acc;
        for (int i = tid; i < 1024; i += 256) wp[256 + i] = Ls[g][1024 + i];
        if (tid < HID) {
            float c = lbs[g][tid];
            for (int i = 0; i < HID; i++) c += bs[g][i] * Ls[g][i * HID + tid];
            wp[1280 + tid] = c;
        }
    }
    for (int i = tid; i < 768; i += 256) ws[OFF_WOUT + i] = Wout[i];
    if (tid < OUTF) ws[OFF_BOUT + tid] = bout[tid];
}

// strip scan: 1024 threads x STRIP elements; also computes dinv. One block.
#define STRIP 49   // ceil(50000/1024)
__global__ __launch_bounds__(1024)
void k_scan(const int* __restrict__ degi, int* __restrict__ rowptr,
            float* __restrict__ dinv) {
    __shared__ int wsum[16];
    int tid = threadIdx.x;
    int lane = tid & 63, wid = tid >> 6;
    int s0 = tid * STRIP;
    int vals[STRIP];
    int sum = 0;
    #pragma unroll
    for (int i = 0; i < STRIP; i++) {
        int idx = s0 + i;
        int d = (idx < NN) ? degi[idx] : 0;
        vals[i] = d;
        sum += d;
        if (idx < NN) dinv[idx] = rsqrtf(1.0f + (float)d);
    }
    int run = sum;
    #pragma unroll
    for (int off = 1; off < 64; off <<= 1) {
        int t = __shfl_up(run, off);
        if (lane >= off) run += t;
    }
    if (lane == 63) wsum[wid] = run;
    __syncthreads();
    if (wid == 0 && lane < 16) {
        int v = wsum[lane];
        #pragma unroll
        for (int off = 1; off < 16; off <<= 1) {
            int t = __shfl_up(v, off);
            if (lane >= off) v += t;
        }
        wsum[lane] = v;
    }
    __syncthreads();
    int base = (wid ? wsum[wid - 1] : 0) + (run - sum);
    if (tid == 0) rowptr[0] = 0;
    #pragma unroll
    for (int i = 0; i < STRIP; i++) {
        int idx = s0 + i;
        if (idx < NN) { base += vals[i]; rowptr[idx + 1] = base; }
    }
}

__global__ void k_csr(const int* __restrict__ src, const int* __restrict__ dst,
                      const int* __restrict__ rowptr, int* __restrict__ cursor,
                      const float* __restrict__ dinv,
                      int* __restrict__ col, float* __restrict__ wgt) {
    int e = blockIdx.x * blockDim.x + threadIdx.x;
    if (e >= NE) return;
    int s = src[e], d = dst[e];
    int pos = atomicAdd(&cursor[d], 1);
    int i = rowptr[d] + pos;
    col[i] = s;
    wgt[i] = dinv[s] * dinv[d];
}

// R11: gridDim.y = 2 batch planes; each thread gathers FULL 384B rows
// (24 x float4, exactly 3 cache lines, zero overfetch).
__global__ __launch_bounds__(256)
void k_agg(const float* __restrict__ x,
           const int* __restrict__ rowptr, const int* __restrict__ col,
           const float* __restrict__ wgt, const float* __restrict__ dinv,
           float* __restrict__ AX) {
    int n = blockIdx.x * blockDim.x + threadIdx.x;
    if (n >= NN) return;
    const float* xb = x + (size_t)blockIdx.y * (NN * FP);   // plane base
    float* axb = AX + (size_t)blockIdx.y * NN + n;          // AX[q*BN + b*NN + n]
    int r0 = rowptr[n], r1 = rowptr[n + 1];

    float4 acc[24];
    #pragma unroll
    for (int c = 0; c < 24; c++) acc[c] = make_float4(0.f, 0.f, 0.f, 0.f);

    #pragma unroll 1
    for (int i = r0; i < r1; i++) {
        int s = col[i];
        float w = wgt[i];
        const float* row = xb + (size_t)s * FP;
        float4 v[24];
        #pragma unroll
        for (int c = 0; c < 24; c++) v[c] = *(const float4*)(row + c * 4);
        __builtin_amdgcn_sched_barrier(0);   // keep all 24 loads clustered
        #pragma unroll
        for (int c = 0; c < 24; c++) {
            acc[c].x = fmaf(w, v[c].x, acc[c].x);
            acc[c].y = fmaf(w, v[c].y, acc[c].y);
            acc[c].z = fmaf(w, v[c].z, acc[c].z);
            acc[c].w = fmaf(w, v[c].w, acc[c].w);
        }
    }
    {   // self loop: weight dinv[n]^2
        float di = dinv[n];
        float w = di * di;
        const float* row = xb + (size_t)n * FP;
        float4 v[24];
        #pragma unroll
        for (int c = 0; c < 24; c++) v[c] = *(const float4*)(row + c * 4);
        __builtin_amdgcn_sched_barrier(0);
        #pragma unroll
        for (int c = 0; c < 24; c++) {
            acc[c].x = fmaf(w, v[c].x, acc[c].x);
            acc[c].y = fmaf(w, v[c].y, acc[c].y);
            acc[c].z = fmaf(w, v[c].z, acc[c].z);
            acc[c].w = fmaf(w, v[c].w, acc[c].w);
        }
    }
    #pragma unroll
    for (int c = 0; c < 24; c++) {
        axb[(size_t)(4 * c + 0) * BN] = acc[c].x;
        axb[(size_t)(4 * c + 1) * BN] = acc[c].y;
        axb[(size_t)(4 * c + 2) * BN] = acc[c].z;
        axb[(size_t)(4 * c + 3) * BN] = acc[c].w;
    }
}

// ----- array-free GRU: X-macros, 2-deep pipelined LDS rows (R12) -----

// deferred concat: expands macro args (GP->o) BEFORE pasting (R12 lesson)
#define XCAT_(a,b) a##b
#define XCAT(a,b) XCAT_(a,b)

#define FOR32(OP) \
    OP(0,x,0)  OP(0,y,1)  OP(0,z,2)  OP(0,w,3) \
    OP(1,x,4)  OP(1,y,5)  OP(1,z,6)  OP(1,w,7) \
    OP(2,x,8)  OP(2,y,9)  OP(2,z,10) OP(2,w,11) \
    OP(3,x,12) OP(3,y,13) OP(3,z,14) OP(3,w,15) \
    OP(4,x,16) OP(4,y,17) OP(4,z,18) OP(4,w,19) \
    OP(5,x,20) OP(5,y,21) OP(5,z,22) OP(5,w,23) \
    OP(6,x,24) OP(6,y,25) OP(6,z,26) OP(6,w,27) \
    OP(7,x,28) OP(7,y,29) OP(7,z,30) OP(7,w,31)

// alternating A/B variants: (i, c, n, CUR, NXT) -- FMA from CUR, load NXT
#define FOR8AB(OP) \
    OP(0,x,0,ua,ub) OP(0,y,1,ub,ua) OP(0,z,2,ua,ub) OP(0,w,3,ub,ua) \
    OP(1,x,4,ua,ub) OP(1,y,5,ub,ua) OP(1,z,6,ua,ub) OP(1,w,7,ub,ua)

#define FOR32AB(OP) \
    OP(0,x,0,ua,ub)  OP(0,y,1,ub,ua)  OP(0,z,2,ua,ub)  OP(0,w,3,ub,ua) \
    OP(1,x,4,ua,ub)  OP(1,y,5,ub,ua)  OP(1,z,6,ua,ub)  OP(1,w,7,ub,ua) \
    OP(2,x,8,ua,ub)  OP(2,y,9,ub,ua)  OP(2,z,10,ua,ub) OP(2,w,11,ub,ua) \
    OP(3,x,12,ua,ub) OP(3,y,13,ub,ua) OP(3,z,14,ua,ub) OP(3,w,15,ub,ua) \
    OP(4,x,16,ua,ub) OP(4,y,17,ub,ua) OP(4,z,18,ua,ub) OP(4,w,19,ub,ua) \
    OP(5,x,20,ua,ub) OP(5,y,21,ub,ua) OP(5,z,22,ua,ub) OP(5,w,23,ub,ua) \
    OP(6,x,24,ua,ub) OP(6,y,25,ub,ua) OP(6,z,26,ua,ub) OP(6,w,27,ub,ua) \
    OP(7,x,28,ua,ub) OP(7,y,29,ub,ua) OP(7,z,30,ua,ub) OP(7,w,31,ub,ua)

// component-wise fma; param names must not be x/y/z/w (R5 lesson)
#define FMA4(dd, ss, vv) \
    dd.x = fmaf((ss), (vv).x, dd.x); dd.y = fmaf((ss), (vv).y, dd.y); \
    dd.z = fmaf((ss), (vv).z, dd.z); dd.w = fmaf((ss), (vv).w, dd.w);

// schedule pin (R8 spill preventer / R12 pipeline stepper)
#define SBAR() __builtin_amdgcn_sched_barrier(0)

// load one 32-float weight row into register set U (8x ds_read_b128)
#define ROWLD(U, W, ofs) \
    XCAT(U,0) = *(const float4*)((W) + (ofs)); \
    XCAT(U,1) = *(const float4*)((W) + (ofs) + 4); \
    XCAT(U,2) = *(const float4*)((W) + (ofs) + 8); \
    XCAT(U,3) = *(const float4*)((W) + (ofs) + 12); \
    XCAT(U,4) = *(const float4*)((W) + (ofs) + 16); \
    XCAT(U,5) = *(const float4*)((W) + (ofs) + 20); \
    XCAT(U,6) = *(const float4*)((W) + (ofs) + 24); \
    XCAT(U,7) = *(const float4*)((W) + (ofs) + 28);

#define ROWFMA(P, a, U) do { \
    float av = (a); \
    FMA4(XCAT(P,0), av, XCAT(U,0)) FMA4(XCAT(P,1), av, XCAT(U,1)) \
    FMA4(XCAT(P,2), av, XCAT(U,2)) FMA4(XCAT(P,3), av, XCAT(U,3)) \
    FMA4(XCAT(P,4), av, XCAT(U,4)) FMA4(XCAT(P,5), av, XCAT(U,5)) \
    FMA4(XCAT(P,6), av, XCAT(U,6)) FMA4(XCAT(P,7), av, XCAT(U,7)) \
} while (0)

#define LDB(P, W) \
    XCAT(P,0) = *(const float4*)((W) + 1280); XCAT(P,1) = *(const float4*)((W) + 1284); \
    XCAT(P,2) = *(const float4*)((W) + 1288); XCAT(P,3) = *(const float4*)((W) + 1292); \
    XCAT(P,4) = *(const float4*)((W) + 1296); XCAT(P,5) = *(const float4*)((W) + 1300); \
    XCAT(P,6) = *(const float4*)((W) + 1304); XCAT(P,7) = *(const float4*)((W) + 1308);

// pipelined steps: load row n+1 into NXT, FMA row n from CUR, pin.
// in-rows: next ofs = 32*(n+1), except n=7 -> 256 (first h-row).
// h-rows:  next ofs = 256+32*(n+1), except n=31 -> redundant reload of 31.
#define GIN_STEP(i,c,n,CUR,NXT) \
    ROWLD(NXT, Wg, ((n) < 7 ? 32*((n)+1) : 256)); \
    ROWFMA(GP, XCAT(in,i).c, CUR); SBAR();

#define GH_STEP(i,c,n,CUR,NXT) \
    ROWLD(NXT, Wg, 256 + 32*((n) < 31 ? (n)+1 : 31)); \
    ROWFMA(GP, XCAT(GS,i).c, CUR); SBAR();

#define GATE_PIPE() \
    LDB(GP, Wg); ROWLD(ua, Wg, 0); SBAR(); \
    FOR8AB(GIN_STEP) \
    FOR32AB(GH_STEP)

#define ZERO_OP(i,c,n) h##i.c = 0.0f; ac##i.c = 0.0f;
#define HR_OP(i,c,n)   o##i.c = sigm(o##i.c) * h##i.c;
#define TANH_OP(i,c,n) t##i.c = tanh_fast(t##i.c);
#define UPD_OP(i,c,n)  { float Zv = sigm(o##i.c); \
                         h##i.c = fmaf(Zv, h##i.c - t##i.c, t##i.c); \
                         ac##i.c = fmaf(pp, h##i.c, ac##i.c); }

#define OROW(a, ofs) do { \
    float4 u0 = *(const float4*)(WO + (ofs)); \
    float4 u1 = *(const float4*)(WO + (ofs) + 4); \
    float4 u2 = *(const float4*)(WO + (ofs) + 8); \
    float4 u3 = *(const float4*)(WO + (ofs) + 12); \
    float4 u4 = *(const float4*)(WO + (ofs) + 16); \
    float4 u5 = *(const float4*)(WO + (ofs) + 20); \
    float av = (a); \
    FMA4(q0, av, u0) FMA4(q1, av, u1) FMA4(q2, av, u2) \
    FMA4(q3, av, u3) FMA4(q4, av, u4) FMA4(q5, av, u5) \
    SBAR(); \
} while (0)

#define OUT_OP(i,c,n) OROW(fmaxf(ac##i.c, 0.0f), (n) * OUTF);

__global__ __launch_bounds__(64)
void k_gru(const float* __restrict__ AX, const float* __restrict__ wp,
           float* __restrict__ out) {
    __shared__ __align__(16) float sm[SM_TOT];
    int tid = threadIdx.x;
    // stage all packed params into LDS once (loop-invariant across periods)
    for (int i = tid; i < SM_TOT; i += 64) sm[i] = wp[i];
    __syncthreads();

    int g = blockIdx.x * 64 + tid;   // g = b*N + n
    if (g >= BN) return;

    const float* WZ = sm + OFF_WPK;
    const float* WR = sm + OFF_WPK + GSTRIDE;
    const float* WH = sm + OFF_WPK + 2 * GSTRIDE;

    float4 h0, h1, h2, h3, h4, h5, h6, h7;
    float4 ac0, ac1, ac2, ac3, ac4, ac5, ac6, ac7;
    float4 o0, o1, o2, o3, o4, o5, o6, o7;
    float4 t0, t1, t2, t3, t4, t5, t6, t7;
    float4 ua0, ua1, ua2, ua3, ua4, ua5, ua6, ua7;
    float4 ub0, ub1, ub2, ub3, ub4, ub5, ub6, ub7;
    float4 in0, in1;
    FOR32(ZERO_OP)

    #pragma unroll 1
    for (int p = 0; p < PER; p++) {
        const float* axp = AX + (size_t)p * BN + g;
        in0.x = axp[0];
        in0.y = axp[(size_t)1 * PER * BN];
        in0.z = axp[(size_t)2 * PER * BN];
        in0.w = axp[(size_t)3 * PER * BN];
        in1.x = axp[(size_t)4 * PER * BN];
        in1.y = axp[(size_t)5 * PER * BN];
        in1.z = axp[(size_t)6 * PER * BN];
        in1.w = axp[(size_t)7 * PER * BN];
        float pp = sm[OFF_PROBS + p];

        // R gate: o = bias + M_r in + L_r H  (source h, target o)
        #define GP o
        #define GS h
        { const float* Wg = WR; GATE_PIPE() }
        #undef GP
        #undef GS
        FOR32(HR_OP)                      // o = sigm(o) * h

        // T gate: t = bias + M_h in + L_h (H*R)  (source o, target t)
        #define GP t
        #define GS o
        { const float* Wg = WH; GATE_PIPE() }
        #undef GP
        #undef GS
        FOR32(TANH_OP)

        // Z gate: o = bias + M_z in + L_z H  (source h, target o)
        #define GP o
        #define GS h
        { const float* Wg = WZ; GATE_PIPE() }
        #undef GP
        #undef GS
        FOR32(UPD_OP)
    }

    // epilogue: relu(acc) @ Wout + bout
    const float* WO = sm + OFF_WOUT;
    const float* WB = sm + OFF_BOUT;
    float4 q0 = *(const float4*)(WB + 0);
    float4 q1 = *(const float4*)(WB + 4);
    float4 q2 = *(const float4*)(WB + 8);
    float4 q3 = *(const float4*)(WB + 12);
    float4 q4 = *(const float4*)(WB + 16);
    float4 q5 = *(const float4*)(WB + 20);
    FOR32(OUT_OP)

    float* op = out + (size_t)g * OUTF;
    *(float4*)(op + 0)  = q0; *(float4*)(op + 4)  = q1;
    *(float4*)(op + 8)  = q2; *(float4*)(op + 12) = q3;
    *(float4*)(op + 16) = q4; *(float4*)(op + 20) = q5;
}

extern "C" void kernel_launch(void* const* d_in, const int* in_sizes, int n_in,
                              void* d_out, int out_size, void* d_ws, size_t ws_size,
                              hipStream_t stream) {
    if (ws_size < (size_t)WS_FLOATS * sizeof(float)) return;  // need ~45.6 MB scratch

    const float* x    = (const float*)d_in[0];
    const int*   ei   = (const int*)d_in[1];
    const float* att  = (const float*)d_in[2];
    const float* Wz   = (const float*)d_in[3];
    const float* bz   = (const float*)d_in[4];
    const float* Wr   = (const float*)d_in[5];
    const float* br   = (const float*)d_in[6];
    const float* Wh   = (const float*)d_in[7];
    const float* bh   = (const float*)d_in[8];
    const float* Lz   = (const float*)d_in[9];
    const float* lbz  = (const float*)d_in[10];
    const float* Lr   = (const float*)d_in[11];
    const float* lbr  = (const float*)d_in[12];
    const float* Lh   = (const float*)d_in[13];
    const float* lbh  = (const float*)d_in[14];
    const float* Wout = (const float*)d_in[15];
    const float* bout = (const float*)d_in[16];
    float* out = (float*)d_out;
    float* ws  = (float*)d_ws;

    const int* src = ei;
    const int* dst = ei + NE;

    float* dinv   = ws + OFF_DINV;
    int*   degi   = (int*)(ws + OFF_DEGI);
    int*   cursor = (int*)(ws + OFF_CURSOR);
    int*   rowptr = (int*)(ws + OFF_ROWPTR);
    int*   col    = (int*)(ws + OFF_COL);
    float* wgt    = ws + OFF_WGT;
    float* AX     = ws + OFF_AX;

    hipMemsetAsync(degi, 0, 2 * (size_t)NN * sizeof(int), stream);
    k_deg<<<(NE + 255) / 256, 256, 0, stream>>>(dst, degi);
    k_prep<<<1, 256, 0, stream>>>(att, Wz, bz, Wr, br, Wh, bh,
                                  Lz, lbz, Lr, lbr, Lh, lbh, Wout, bout, ws);
    k_scan<<<1, 1024, 0, stream>>>(degi, rowptr, dinv);
    k_csr<<<(NE + 255) / 256, 256, 0, stream>>>(src, dst, rowptr, cursor, dinv, col, wgt);
    dim3 gAgg((NN + 255) / 256, 2);
    k_agg<<<gAgg, 256, 0, stream>>>(x, rowptr, col, wgt, dinv, AX);
    k_gru<<<(BN + 63) / 64, 64, 0, stream>>>(AX, ws, out);
}